// Round 1
// baseline (1314.490 us; speedup 1.0000x reference)
//
#include <hip/hip_runtime.h>
#include <math.h>

// Problem constants (B,N,D,H,HD) = (2, 2048, 1024, 16, 64)
namespace {
constexpr int kB  = 2;
constexpr int kN  = 2048;
constexpr int kD  = 1024;
constexpr int kH  = 16;
constexpr int kM  = kB * kN;   // 4096 rows
}

// ---------------------------------------------------------------------------
// C[M,Nc] = A[M,K] @ W[K,Nc] + bias  (fp32, 64x64 tile, BK=16, 4x4/thread)
// ---------------------------------------------------------------------------
__global__ __launch_bounds__(256)
void gemm_bias_64(const float* __restrict__ A, const float* __restrict__ W,
                  const float* __restrict__ bias, float* __restrict__ C,
                  int M, int K, int Nc)
{
    __shared__ float sA[16][64];   // sA[k][i]
    __shared__ float sB[16][64];   // sB[k][j]

    const int tid  = threadIdx.x;
    const int row0 = blockIdx.y << 6;
    const int col0 = blockIdx.x << 6;
    const int tr   = tid >> 4;     // 0..15
    const int tc   = tid & 15;     // 0..15

    // A-tile load mapping: one float4 per thread (64 rows x 16 k)
    const int ai = tid >> 2;            // row in tile
    const int ak = (tid & 3) << 2;      // k in tile
    // B-tile load mapping: one float4 per thread (16 k x 64 cols)
    const int bk = tid >> 4;
    const int bj = (tid & 15) << 2;

    const float* Ap = A + (size_t)(row0 + ai) * K + ak;
    const float* Wp = W + (size_t)bk * Nc + (col0 + bj);

    float acc[4][4] = {};

    for (int k0 = 0; k0 < K; k0 += 16) {
        const float4 av = *(const float4*)(Ap + k0);
        const float4 bv = *(const float4*)(Wp + (size_t)k0 * Nc);
        __syncthreads();             // previous iteration's compute done
        sA[ak + 0][ai] = av.x;
        sA[ak + 1][ai] = av.y;
        sA[ak + 2][ai] = av.z;
        sA[ak + 3][ai] = av.w;
        *(float4*)&sB[bk][bj] = bv;
        __syncthreads();
#pragma unroll
        for (int k = 0; k < 16; ++k) {
            float a[4], b[4];
            *(float4*)a = *(const float4*)&sA[k][tr << 2];
            *(float4*)b = *(const float4*)&sB[k][tc << 2];
#pragma unroll
            for (int r = 0; r < 4; ++r)
#pragma unroll
                for (int c = 0; c < 4; ++c)
                    acc[r][c] = fmaf(a[r], b[c], acc[r][c]);
        }
    }

    const int col = col0 + (tc << 2);
#pragma unroll
    for (int r = 0; r < 4; ++r) {
        float4 o;
        o.x = acc[r][0] + bias[col + 0];
        o.y = acc[r][1] + bias[col + 1];
        o.z = acc[r][2] + bias[col + 2];
        o.w = acc[r][3] + bias[col + 3];
        *(float4*)(C + (size_t)(row0 + (tr << 2) + r) * Nc + col) = o;
    }
}

// ---------------------------------------------------------------------------
// Flash attention with Gaussian bias.
// Block: 256 threads = one (b,h) x 64 Q-rows.  KV tiles of 64.
// Q,K,V live in (B,N,D) layout; head slice = cols [h*64, h*64+64).
// LDS: sQ[64][65], sKP[64][65] (K then P, shared), sV[64][65]  = 48.75 KB.
// ---------------------------------------------------------------------------
__global__ __launch_bounds__(256)
void attn64(const float* __restrict__ Qm, const float* __restrict__ Km,
            const float* __restrict__ Vm, const float* __restrict__ Bg,
            const float* __restrict__ lam_p, float* __restrict__ AO)
{
    __shared__ float sQ [64][65];
    __shared__ float sKP[64][65];   // K-tile during S, P-tile during PV
    __shared__ float sV [64][65];

    const int tid = threadIdx.x;
    const int qt  = blockIdx.x;          // 0..31
    const int bh  = blockIdx.y;          // 0..31
    const int b   = bh >> 4;
    const int h   = bh & 15;
    const int i0  = qt << 6;

    const float lam   = *lam_p;
    const float scale = 0.125f;          // 1/sqrt(64)

    const int tr = tid >> 4;             // 0..15 (row group)
    const int tc = tid & 15;             // 0..15 (col group)
    const int ir = tr << 2;              // first of this thread's 4 rows
    const int jc = tc << 2;              // first of this thread's 4 cols

    // ---- load Q tile (64x64) ----
#pragma unroll
    for (int rep = 0; rep < 4; ++rep) {
        const int idx = tid + (rep << 8);      // 0..1023 float4 slots
        const int i   = idx >> 4;
        const int k4  = (idx & 15) << 2;
        const float4 v = *(const float4*)(Qm + ((size_t)(b * kN + i0 + i)) * kD + h * 64 + k4);
        sQ[i][k4 + 0] = v.x; sQ[i][k4 + 1] = v.y;
        sQ[i][k4 + 2] = v.z; sQ[i][k4 + 3] = v.w;
    }

    float O[4][4] = {};
    float m_run[4], l_run[4];
#pragma unroll
    for (int r = 0; r < 4; ++r) { m_run[r] = -INFINITY; l_run[r] = 0.f; }

    const float* BgRow = Bg + (size_t)b * kN * kN + (size_t)i0 * kN;

    for (int jt = 0; jt < kN / 64; ++jt) {
        const int j0 = jt << 6;

        // ---- prefetch to registers (global; before barrier) ----
        float4 kreg[4], vreg[4], bg[4];
#pragma unroll
        for (int rep = 0; rep < 4; ++rep) {
            const int idx = tid + (rep << 8);
            const int j   = idx >> 4;
            const int k4  = (idx & 15) << 2;
            const size_t base = ((size_t)(b * kN + j0 + j)) * kD + h * 64 + k4;
            kreg[rep] = *(const float4*)(Km + base);
            vreg[rep] = *(const float4*)(Vm + base);
        }
#pragma unroll
        for (int r = 0; r < 4; ++r)
            bg[r] = *(const float4*)(BgRow + (size_t)(ir + r) * kN + j0 + jc);

        __syncthreads();                  // prev PV (reads sKP,sV) done
#pragma unroll
        for (int rep = 0; rep < 4; ++rep) {
            const int idx = tid + (rep << 8);
            const int j   = idx >> 4;
            const int k4  = (idx & 15) << 2;
            sKP[j][k4 + 0] = kreg[rep].x; sKP[j][k4 + 1] = kreg[rep].y;
            sKP[j][k4 + 2] = kreg[rep].z; sKP[j][k4 + 3] = kreg[rep].w;
            sV [j][k4 + 0] = vreg[rep].x; sV [j][k4 + 1] = vreg[rep].y;
            sV [j][k4 + 2] = vreg[rep].z; sV [j][k4 + 3] = vreg[rep].w;
        }
        __syncthreads();

        // ---- S = Q K^T (this thread: rows ir..ir+3, cols jc..jc+3) ----
        float s[4][4] = {};
#pragma unroll 4
        for (int k = 0; k < 64; ++k) {
            float a[4], bb[4];
#pragma unroll
            for (int r = 0; r < 4; ++r) a[r]  = sQ [ir + r][k];
#pragma unroll
            for (int c = 0; c < 4; ++c) bb[c] = sKP[jc + c][k];
#pragma unroll
            for (int r = 0; r < 4; ++r)
#pragma unroll
                for (int c = 0; c < 4; ++c)
                    s[r][c] = fmaf(a[r], bb[c], s[r][c]);
        }

        // ---- scale + Gaussian bias, online softmax (stats replicated
        //      across the 16-lane row group via shfl) ----
        float p[4][4];
#pragma unroll
        for (int r = 0; r < 4; ++r) {
            s[r][0] = fmaf(lam, bg[r].x, s[r][0] * scale);
            s[r][1] = fmaf(lam, bg[r].y, s[r][1] * scale);
            s[r][2] = fmaf(lam, bg[r].z, s[r][2] * scale);
            s[r][3] = fmaf(lam, bg[r].w, s[r][3] * scale);

            float mt = fmaxf(fmaxf(s[r][0], s[r][1]), fmaxf(s[r][2], s[r][3]));
            mt = fmaxf(mt, __shfl_xor(mt, 1, 16));
            mt = fmaxf(mt, __shfl_xor(mt, 2, 16));
            mt = fmaxf(mt, __shfl_xor(mt, 4, 16));
            mt = fmaxf(mt, __shfl_xor(mt, 8, 16));

            const float m_new = fmaxf(m_run[r], mt);
            const float alpha = __expf(m_run[r] - m_new);
            p[r][0] = __expf(s[r][0] - m_new);
            p[r][1] = __expf(s[r][1] - m_new);
            p[r][2] = __expf(s[r][2] - m_new);
            p[r][3] = __expf(s[r][3] - m_new);
            float ls = (p[r][0] + p[r][1]) + (p[r][2] + p[r][3]);
            ls += __shfl_xor(ls, 1, 16);
            ls += __shfl_xor(ls, 2, 16);
            ls += __shfl_xor(ls, 4, 16);
            ls += __shfl_xor(ls, 8, 16);
            l_run[r] = l_run[r] * alpha + ls;
            m_run[r] = m_new;
            O[r][0] *= alpha; O[r][1] *= alpha; O[r][2] *= alpha; O[r][3] *= alpha;
        }

        __syncthreads();                  // everyone done reading K from sKP
#pragma unroll
        for (int r = 0; r < 4; ++r) {
            sKP[ir + r][jc + 0] = p[r][0];
            sKP[ir + r][jc + 1] = p[r][1];
            sKP[ir + r][jc + 2] = p[r][2];
            sKP[ir + r][jc + 3] = p[r][3];
        }
        __syncthreads();

        // ---- O += P @ V ----
#pragma unroll 4
        for (int j = 0; j < 64; ++j) {
            float pr[4], vv[4];
#pragma unroll
            for (int r = 0; r < 4; ++r) pr[r] = sKP[ir + r][j];
#pragma unroll
            for (int c = 0; c < 4; ++c) vv[c] = sV[j][jc + c];
#pragma unroll
            for (int r = 0; r < 4; ++r)
#pragma unroll
                for (int c = 0; c < 4; ++c)
                    O[r][c] = fmaf(pr[r], vv[c], O[r][c]);
        }
    }

    // ---- normalize and store (B,N,D layout) ----
#pragma unroll
    for (int r = 0; r < 4; ++r) {
        const float inv = 1.0f / l_run[r];
        float4 o;
        o.x = O[r][0] * inv; o.y = O[r][1] * inv;
        o.z = O[r][2] * inv; o.w = O[r][3] * inv;
        *(float4*)(AO + (size_t)(b * kN + i0 + ir + r) * kD + h * 64 + jc) = o;
    }
}

// ---------------------------------------------------------------------------
extern "C" void kernel_launch(void* const* d_in, const int* in_sizes, int n_in,
                              void* d_out, int out_size, void* d_ws, size_t ws_size,
                              hipStream_t stream)
{
    (void)in_sizes; (void)n_in; (void)out_size; (void)ws_size;

    const float* x   = (const float*)d_in[0];
    const float* Bg  = (const float*)d_in[1];
    const float* Wq  = (const float*)d_in[2];
    const float* bq  = (const float*)d_in[3];
    const float* Wk  = (const float*)d_in[4];
    const float* bk  = (const float*)d_in[5];
    const float* Wv  = (const float*)d_in[6];
    const float* bv  = (const float*)d_in[7];
    const float* Wo  = (const float*)d_in[8];
    const float* bo  = (const float*)d_in[9];
    const float* lam = (const float*)d_in[10];
    float* out = (float*)d_out;
    float* ws  = (float*)d_ws;

    float* Qb = ws;
    float* Kb = ws + (size_t)kM * kD;
    float* Vb = ws + 2 * (size_t)kM * kD;
    float* AO = ws + 3 * (size_t)kM * kD;      // 4 x 16.8 MB = 67 MB of ws

    dim3 blk(256);
    dim3 ggrid(kD / 64, kM / 64);              // (16, 64)
    gemm_bias_64<<<ggrid, blk, 0, stream>>>(x, Wq, bq, Qb, kM, kD, kD);
    gemm_bias_64<<<ggrid, blk, 0, stream>>>(x, Wk, bk, Kb, kM, kD, kD);
    gemm_bias_64<<<ggrid, blk, 0, stream>>>(x, Wv, bv, Vb, kM, kD, kD);

    dim3 agrid(kN / 64, kB * kH);              // (32, 32)
    attn64<<<agrid, blk, 0, stream>>>(Qb, Kb, Vb, Bg, lam, AO);

    gemm_bias_64<<<ggrid, blk, 0, stream>>>(AO, Wo, bo, out, kM, kD, kD);
}

// Round 2
// 834.443 us; speedup vs baseline: 1.5753x; 1.5753x over previous
//
#include <hip/hip_runtime.h>
#include <math.h>
#include <stdint.h>

// Problem constants (B,N,D,H,HD) = (2, 2048, 1024, 16, 64)
namespace {
constexpr int kB  = 2;
constexpr int kN  = 2048;
constexpr int kD  = 1024;
constexpr int kH  = 16;
constexpr int kM  = kB * kN;   // 4096 rows
}

typedef __attribute__((ext_vector_type(8))) short bf16x8;
typedef __attribute__((ext_vector_type(4))) float f32x4;

__device__ __forceinline__ uint16_t f2bf(float f) {
    uint32_t u = __builtin_bit_cast(uint32_t, f);
    uint32_t r = (u + 0x7fffu + ((u >> 16) & 1u)) >> 16;
    return (uint16_t)r;
}
__device__ __forceinline__ float bf2f(uint16_t h) {
    uint32_t u = ((uint32_t)h) << 16;
    return __builtin_bit_cast(float, u);
}

// ---------------------------------------------------------------------------
// C[M,Nc] = A[M,K] @ W[K,Nc] + bias  (fp32, 64x64 tile, BK=16, 4x4/thread)
// ---------------------------------------------------------------------------
__global__ __launch_bounds__(256)
void gemm_bias_64(const float* __restrict__ A, const float* __restrict__ W,
                  const float* __restrict__ bias, float* __restrict__ C,
                  int M, int K, int Nc)
{
    __shared__ float sA[16][64];   // sA[k][i]
    __shared__ float sB[16][64];   // sB[k][j]

    const int tid  = threadIdx.x;
    const int row0 = blockIdx.y << 6;
    const int col0 = blockIdx.x << 6;
    const int tr   = tid >> 4;
    const int tc   = tid & 15;

    const int ai = tid >> 2;
    const int ak = (tid & 3) << 2;
    const int bk = tid >> 4;
    const int bj = (tid & 15) << 2;

    const float* Ap = A + (size_t)(row0 + ai) * K + ak;
    const float* Wp = W + (size_t)bk * Nc + (col0 + bj);

    float acc[4][4] = {};

    for (int k0 = 0; k0 < K; k0 += 16) {
        const float4 av = *(const float4*)(Ap + k0);
        const float4 bv = *(const float4*)(Wp + (size_t)k0 * Nc);
        __syncthreads();
        sA[ak + 0][ai] = av.x;
        sA[ak + 1][ai] = av.y;
        sA[ak + 2][ai] = av.z;
        sA[ak + 3][ai] = av.w;
        *(float4*)&sB[bk][bj] = bv;
        __syncthreads();
#pragma unroll
        for (int k = 0; k < 16; ++k) {
            float a[4], b[4];
            *(float4*)a = *(const float4*)&sA[k][tr << 2];
            *(float4*)b = *(const float4*)&sB[k][tc << 2];
#pragma unroll
            for (int r = 0; r < 4; ++r)
#pragma unroll
                for (int c = 0; c < 4; ++c)
                    acc[r][c] = fmaf(a[r], b[c], acc[r][c]);
        }
    }

    const int col = col0 + (tc << 2);
#pragma unroll
    for (int r = 0; r < 4; ++r) {
        float4 o;
        o.x = acc[r][0] + bias[col + 0];
        o.y = acc[r][1] + bias[col + 1];
        o.z = acc[r][2] + bias[col + 2];
        o.w = acc[r][3] + bias[col + 3];
        *(float4*)(C + (size_t)(row0 + (tr << 2) + r) * Nc + col) = o;
    }
}

// ---------------------------------------------------------------------------
// Same GEMM but stores TRANSPOSED output: Vt[(b*kD + col)*kN + n] where
// row = b*kN + n (token), col = h*64 + d.  Thread's 4 acc rows are
// consecutive tokens -> float4 store along n (no LDS transpose needed).
// ---------------------------------------------------------------------------
__global__ __launch_bounds__(256)
void gemm_bias_64_vt(const float* __restrict__ A, const float* __restrict__ W,
                     const float* __restrict__ bias, float* __restrict__ Vt,
                     int M, int K, int Nc)
{
    __shared__ float sA[16][64];
    __shared__ float sB[16][64];

    const int tid  = threadIdx.x;
    const int row0 = blockIdx.y << 6;
    const int col0 = blockIdx.x << 6;
    const int tr   = tid >> 4;
    const int tc   = tid & 15;

    const int ai = tid >> 2;
    const int ak = (tid & 3) << 2;
    const int bk = tid >> 4;
    const int bj = (tid & 15) << 2;

    const float* Ap = A + (size_t)(row0 + ai) * K + ak;
    const float* Wp = W + (size_t)bk * Nc + (col0 + bj);

    float acc[4][4] = {};

    for (int k0 = 0; k0 < K; k0 += 16) {
        const float4 av = *(const float4*)(Ap + k0);
        const float4 bv = *(const float4*)(Wp + (size_t)k0 * Nc);
        __syncthreads();
        sA[ak + 0][ai] = av.x;
        sA[ak + 1][ai] = av.y;
        sA[ak + 2][ai] = av.z;
        sA[ak + 3][ai] = av.w;
        *(float4*)&sB[bk][bj] = bv;
        __syncthreads();
#pragma unroll
        for (int k = 0; k < 16; ++k) {
            float a[4], b[4];
            *(float4*)a = *(const float4*)&sA[k][tr << 2];
            *(float4*)b = *(const float4*)&sB[k][tc << 2];
#pragma unroll
            for (int r = 0; r < 4; ++r)
#pragma unroll
                for (int c = 0; c < 4; ++c)
                    acc[r][c] = fmaf(a[r], b[c], acc[r][c]);
        }
    }

    const int row = row0 + (tr << 2);   // 4 consecutive global token rows
    const int bb  = row >> 11;          // batch index
    const int n   = row & (kN - 1);     // token within batch
#pragma unroll
    for (int c = 0; c < 4; ++c) {
        const int col = col0 + (tc << 2) + c;
        const float bc = bias[col];
        float4 o;
        o.x = acc[0][c] + bc; o.y = acc[1][c] + bc;
        o.z = acc[2][c] + bc; o.w = acc[3][c] + bc;
        *(float4*)(Vt + ((size_t)(bb * kD + col)) * kN + n) = o;
    }
}

// ---------------------------------------------------------------------------
// MFMA flash attention with Gaussian bias, split-bf16 (hi+lo, 3-term).
// Block: 256 threads = 4 waves; wave w owns Q-rows [i0+16w, i0+16w+16).
// 16x16x32 bf16 MFMA.  A-frag: m=lane&15, k=quad*8+j.  B-frag: n=lane&15,
// k=quad*8+j.  C/D: col=lane&15, row=quad*4+reg.  (guide-verified layouts)
// ---------------------------------------------------------------------------
__global__ __launch_bounds__(256)
void attn_mfma(const float* __restrict__ Qm, const float* __restrict__ Km,
               const float* __restrict__ Vt, const float* __restrict__ Bg,
               const float* __restrict__ lam_p, float* __restrict__ AO)
{
    __shared__ uint16_t sKh[64][72], sKl[64][72];
    __shared__ uint16_t sVh[64][72], sVl[64][72];
    __shared__ uint16_t sPh[4][16][72], sPl[4][16][72];

    const int tid  = threadIdx.x;
    const int lane = tid & 63;
    const int w    = tid >> 6;       // wave 0..3
    const int quad = lane >> 4;      // 0..3
    const int m16  = lane & 15;

    const int qt = blockIdx.x;       // i-tile 0..31
    const int bh = blockIdx.y;       // 0..31
    const int b  = bh >> 4;
    const int h  = bh & 15;
    const int i0 = qt << 6;

    const float lam   = *lam_p;
    const float scale = 0.125f;      // 1/sqrt(64)

    // ---- Q A-frags direct from global into registers (held all kernel) ----
    bf16x8 qh[2], ql[2];
    {
        const float* qp = Qm + (size_t)(b * kN + i0 + w * 16 + m16) * kD
                          + h * 64 + quad * 8;
#pragma unroll
        for (int ks = 0; ks < 2; ++ks) {
            const float4 v0 = *(const float4*)(qp + ks * 32);
            const float4 v1 = *(const float4*)(qp + ks * 32 + 4);
            const float vv[8] = {v0.x, v0.y, v0.z, v0.w, v1.x, v1.y, v1.z, v1.w};
#pragma unroll
            for (int j = 0; j < 8; ++j) {
                const uint16_t hb = f2bf(vv[j]);
                qh[ks][j] = (short)hb;
                ql[ks][j] = (short)f2bf(vv[j] - bf2f(hb));
            }
        }
    }

    f32x4 O[4];
#pragma unroll
    for (int ds = 0; ds < 4; ++ds) O[ds] = (f32x4){0.f, 0.f, 0.f, 0.f};
    float m_run[4], l_run[4];
#pragma unroll
    for (int r = 0; r < 4; ++r) { m_run[r] = -INFINITY; l_run[r] = 0.f; }

    const size_t bgbase = (size_t)b * kN * kN
                        + (size_t)(i0 + w * 16 + quad * 4) * kN;

    for (int jt = 0; jt < kN / 64; ++jt) {
        const int j0 = jt << 6;

        // ---- prefetch K tile, Vt tile, Bg block to registers ----
        float4 kf[4], vf[4];
#pragma unroll
        for (int rep = 0; rep < 4; ++rep) {
            const int idx = tid + (rep << 8);
            const int row = idx >> 4;            // 0..63
            const int c4  = (idx & 15) << 2;     // 0..60
            kf[rep] = *(const float4*)(Km + (size_t)(b * kN + j0 + row) * kD
                                       + h * 64 + c4);
            vf[rep] = *(const float4*)(Vt + ((size_t)(b * kD + h * 64 + row)) * kN
                                       + j0 + c4);
        }
        float bg[4][4];
#pragma unroll
        for (int js = 0; js < 4; ++js)
#pragma unroll
            for (int r = 0; r < 4; ++r)
                bg[js][r] = Bg[bgbase + (size_t)r * kN + j0 + js * 16 + m16];

        __syncthreads();                 // prev j-tile done reading sK/sV
#pragma unroll
        for (int rep = 0; rep < 4; ++rep) {
            const int idx = tid + (rep << 8);
            const int row = idx >> 4;
            const int c4  = (idx & 15) << 2;
            const float kv[4] = {kf[rep].x, kf[rep].y, kf[rep].z, kf[rep].w};
            const float vv[4] = {vf[rep].x, vf[rep].y, vf[rep].z, vf[rep].w};
            {
                const uint16_t a0 = f2bf(kv[0]), a1 = f2bf(kv[1]),
                               a2 = f2bf(kv[2]), a3 = f2bf(kv[3]);
                const uint16_t b0 = f2bf(kv[0] - bf2f(a0)), b1 = f2bf(kv[1] - bf2f(a1)),
                               b2 = f2bf(kv[2] - bf2f(a2)), b3 = f2bf(kv[3] - bf2f(a3));
                *(uint2*)&sKh[row][c4] =
                    make_uint2((uint32_t)a0 | ((uint32_t)a1 << 16),
                               (uint32_t)a2 | ((uint32_t)a3 << 16));
                *(uint2*)&sKl[row][c4] =
                    make_uint2((uint32_t)b0 | ((uint32_t)b1 << 16),
                               (uint32_t)b2 | ((uint32_t)b3 << 16));
            }
            {
                const uint16_t a0 = f2bf(vv[0]), a1 = f2bf(vv[1]),
                               a2 = f2bf(vv[2]), a3 = f2bf(vv[3]);
                const uint16_t b0 = f2bf(vv[0] - bf2f(a0)), b1 = f2bf(vv[1] - bf2f(a1)),
                               b2 = f2bf(vv[2] - bf2f(a2)), b3 = f2bf(vv[3] - bf2f(a3));
                *(uint2*)&sVh[row][c4] =
                    make_uint2((uint32_t)a0 | ((uint32_t)a1 << 16),
                               (uint32_t)a2 | ((uint32_t)a3 << 16));
                *(uint2*)&sVl[row][c4] =
                    make_uint2((uint32_t)b0 | ((uint32_t)b1 << 16),
                               (uint32_t)b2 | ((uint32_t)b3 << 16));
            }
        }
        __syncthreads();

        // ---- S = Q K^T  (3-term split-bf16 MFMA) ----
        f32x4 sacc[4];
#pragma unroll
        for (int js = 0; js < 4; ++js) {
            f32x4 s = (f32x4){0.f, 0.f, 0.f, 0.f};
#pragma unroll
            for (int ks = 0; ks < 2; ++ks) {
                const bf16x8 khf = *(const bf16x8*)&sKh[js * 16 + m16][ks * 32 + quad * 8];
                const bf16x8 klf = *(const bf16x8*)&sKl[js * 16 + m16][ks * 32 + quad * 8];
                s = __builtin_amdgcn_mfma_f32_16x16x32_bf16(qh[ks], khf, s, 0, 0, 0);
                s = __builtin_amdgcn_mfma_f32_16x16x32_bf16(qh[ks], klf, s, 0, 0, 0);
                s = __builtin_amdgcn_mfma_f32_16x16x32_bf16(ql[ks], khf, s, 0, 0, 0);
            }
            sacc[js] = s;
        }

        // ---- online softmax (rows = quad*4+reg; cols across 16-lane group) ----
        float p[4][4];   // [jsub][reg]
        float alpha[4];
#pragma unroll
        for (int r = 0; r < 4; ++r) {
            float val[4];
#pragma unroll
            for (int js = 0; js < 4; ++js)
                val[js] = fmaf(lam, bg[js][r], sacc[js][r] * scale);
            float mt = fmaxf(fmaxf(val[0], val[1]), fmaxf(val[2], val[3]));
            mt = fmaxf(mt, __shfl_xor(mt, 1, 16));
            mt = fmaxf(mt, __shfl_xor(mt, 2, 16));
            mt = fmaxf(mt, __shfl_xor(mt, 4, 16));
            mt = fmaxf(mt, __shfl_xor(mt, 8, 16));
            const float mnew = fmaxf(m_run[r], mt);
            alpha[r] = __expf(m_run[r] - mnew);
#pragma unroll
            for (int js = 0; js < 4; ++js) p[js][r] = __expf(val[js] - mnew);
            float ls = (p[0][r] + p[1][r]) + (p[2][r] + p[3][r]);
            ls += __shfl_xor(ls, 1, 16);
            ls += __shfl_xor(ls, 2, 16);
            ls += __shfl_xor(ls, 4, 16);
            ls += __shfl_xor(ls, 8, 16);
            l_run[r] = l_run[r] * alpha[r] + ls;
            m_run[r] = mnew;
        }
#pragma unroll
        for (int ds = 0; ds < 4; ++ds)
#pragma unroll
            for (int r = 0; r < 4; ++r) O[ds][r] *= alpha[r];

        // ---- P -> wave-private LDS (C-layout -> A-layout), split h/l ----
#pragma unroll
        for (int js = 0; js < 4; ++js)
#pragma unroll
            for (int r = 0; r < 4; ++r) {
                const uint16_t hb = f2bf(p[js][r]);
                sPh[w][quad * 4 + r][js * 16 + m16] = hb;
                sPl[w][quad * 4 + r][js * 16 + m16] = f2bf(p[js][r] - bf2f(hb));
            }
        __asm__ volatile("s_waitcnt lgkmcnt(0)" ::: "memory");

        // ---- O += P V  (3-term split-bf16 MFMA) ----
#pragma unroll
        for (int ks = 0; ks < 2; ++ks) {
            const bf16x8 phf = *(const bf16x8*)&sPh[w][m16][ks * 32 + quad * 8];
            const bf16x8 plf = *(const bf16x8*)&sPl[w][m16][ks * 32 + quad * 8];
#pragma unroll
            for (int ds = 0; ds < 4; ++ds) {
                const bf16x8 vhf = *(const bf16x8*)&sVh[ds * 16 + m16][ks * 32 + quad * 8];
                const bf16x8 vlf = *(const bf16x8*)&sVl[ds * 16 + m16][ks * 32 + quad * 8];
                O[ds] = __builtin_amdgcn_mfma_f32_16x16x32_bf16(phf, vhf, O[ds], 0, 0, 0);
                O[ds] = __builtin_amdgcn_mfma_f32_16x16x32_bf16(phf, vlf, O[ds], 0, 0, 0);
                O[ds] = __builtin_amdgcn_mfma_f32_16x16x32_bf16(plf, vhf, O[ds], 0, 0, 0);
            }
        }
    }

    // ---- normalize and store ----
    const int orow = b * kN + i0 + w * 16 + quad * 4;
#pragma unroll
    for (int r = 0; r < 4; ++r) {
        const float inv = 1.0f / l_run[r];
#pragma unroll
        for (int ds = 0; ds < 4; ++ds)
            AO[(size_t)(orow + r) * kD + h * 64 + ds * 16 + m16] = O[ds][r] * inv;
    }
}

// ---------------------------------------------------------------------------
extern "C" void kernel_launch(void* const* d_in, const int* in_sizes, int n_in,
                              void* d_out, int out_size, void* d_ws, size_t ws_size,
                              hipStream_t stream)
{
    (void)in_sizes; (void)n_in; (void)out_size; (void)ws_size;

    const float* x   = (const float*)d_in[0];
    const float* Bg  = (const float*)d_in[1];
    const float* Wq  = (const float*)d_in[2];
    const float* bq  = (const float*)d_in[3];
    const float* Wk  = (const float*)d_in[4];
    const float* bk  = (const float*)d_in[5];
    const float* Wv  = (const float*)d_in[6];
    const float* bv  = (const float*)d_in[7];
    const float* Wo  = (const float*)d_in[8];
    const float* bo  = (const float*)d_in[9];
    const float* lam = (const float*)d_in[10];
    float* out = (float*)d_out;
    float* ws  = (float*)d_ws;

    float* Qb = ws;
    float* Kb = ws + (size_t)kM * kD;
    float* Vt = ws + 2 * (size_t)kM * kD;      // transposed V (b, h*64+d, n)
    float* AO = ws + 3 * (size_t)kM * kD;

    dim3 blk(256);
    dim3 ggrid(kD / 64, kM / 64);              // (16, 64)
    gemm_bias_64   <<<ggrid, blk, 0, stream>>>(x, Wq, bq, Qb, kM, kD, kD);
    gemm_bias_64   <<<ggrid, blk, 0, stream>>>(x, Wk, bk, Kb, kM, kD, kD);
    gemm_bias_64_vt<<<ggrid, blk, 0, stream>>>(x, Wv, bv, Vt, kM, kD, kD);

    dim3 agrid(kN / 64, kB * kH);              // (32, 32)
    attn_mfma<<<agrid, blk, 0, stream>>>(Qb, Kb, Vt, Bg, lam, AO);

    gemm_bias_64<<<ggrid, blk, 0, stream>>>(AO, Wo, bo, out, kM, kD, kD);
}

// Round 3
// 602.728 us; speedup vs baseline: 2.1809x; 1.3844x over previous
//
#include <hip/hip_runtime.h>
#include <math.h>
#include <stdint.h>

// Problem constants (B,N,D,H,HD) = (2, 2048, 1024, 16, 64)
namespace {
constexpr int kB  = 2;
constexpr int kN  = 2048;
constexpr int kD  = 1024;
constexpr int kH  = 16;
constexpr int kM  = kB * kN;   // 4096 rows
}

typedef __attribute__((ext_vector_type(8))) _Float16 f16x8;
typedef __attribute__((ext_vector_type(4))) float    f32x4;

__device__ __forceinline__ void split16(float v, _Float16& h, _Float16& l) {
    h = (_Float16)v;
    l = (_Float16)(v - (float)h);
}

// ---------------------------------------------------------------------------
// One-shot weight prep: W[k][n] fp32 -> Wt[n][k] split fp16 (h,l).
// grid (K/64, N/64), 256 threads.
// ---------------------------------------------------------------------------
__global__ __launch_bounds__(256)
void wsplit_t(const float* __restrict__ W, _Float16* __restrict__ Oh,
              _Float16* __restrict__ Ol)
{
    __shared__ float sT[64][69];   // odd-ish pitch to break column-read conflicts
    const int tid = threadIdx.x;
    const int k0 = blockIdx.x << 6;
    const int n0 = blockIdx.y << 6;
#pragma unroll
    for (int rep = 0; rep < 4; ++rep) {
        const int idx = tid + (rep << 8);
        const int kr  = idx >> 4;
        const int c4  = (idx & 15) << 2;
        const float4 v = *(const float4*)(W + (size_t)(k0 + kr) * kD + n0 + c4);
        sT[kr][c4 + 0] = v.x; sT[kr][c4 + 1] = v.y;
        sT[kr][c4 + 2] = v.z; sT[kr][c4 + 3] = v.w;
    }
    __syncthreads();
#pragma unroll
    for (int rep = 0; rep < 2; ++rep) {
        const int slot = tid + (rep << 8);
        const int n  = slot >> 3;
        const int k8 = (slot & 7) << 3;
        _Float16 h8[8], l8[8];
#pragma unroll
        for (int j = 0; j < 8; ++j) {
            const float f = sT[k8 + j][n];
            split16(f, h8[j], l8[j]);
        }
        *(uint4*)(Oh + (size_t)(n0 + n) * kD + k0 + k8) = *(uint4*)h8;
        *(uint4*)(Ol + (size_t)(n0 + n) * kD + k0 + k8) = *(uint4*)l8;
    }
}

// ---------------------------------------------------------------------------
// Split-fp16 MFMA GEMM: C[M=4096][1024] = A[4096][1024] @ W[1024][1024] + b.
// B pre-transposed+split: Bh/Bl = Wt[n][k] fp16.
// a_kind 0: A fp32, split in staging, 3-term (hh + hl + lh).
// a_kind 1: A fp16 single, 2-term (hh + hl).
// epi 0: fp32 + bias -> Cf.   epi 1: split-f16 -> Oh/Ol ([m][n]).
// epi 2: split-f16 transposed -> Oh/Ol as [b*kD+n][kN + tok] (for V).
// Tile 128(M)x64(N), BK=64, 4 waves (2x2 of 64x32), register prefetch.
// ---------------------------------------------------------------------------
__global__ __launch_bounds__(256)
void gemm_split(const float* __restrict__ Af32, const _Float16* __restrict__ Af16,
                const _Float16* __restrict__ Bh, const _Float16* __restrict__ Bl,
                const float* __restrict__ bias, float* __restrict__ Cf,
                _Float16* __restrict__ Oh, _Float16* __restrict__ Ol,
                int a_kind, int epi)
{
    union Sh {
        struct { _Float16 Ah[128][72], Al[128][72], Bh[64][72], Bl[64][72]; } s;
        struct { _Float16 Th[64][136], Tl[64][136]; } t;   // epilogue transpose
    };
    __shared__ Sh U;

    const int tid  = threadIdx.x;
    const int lane = tid & 63;
    const int w    = tid >> 6;
    const int quad = lane >> 4;
    const int m16  = lane & 15;
    const int wrow = (w >> 1) << 6;   // 0 / 64
    const int wcol = (w & 1) << 5;    // 0 / 32

    const int row0 = blockIdx.y << 7;   // M tile
    const int col0 = blockIdx.x << 6;   // N tile

    f32x4 acc[4][2];
#pragma unroll
    for (int mr = 0; mr < 4; ++mr)
#pragma unroll
        for (int nr = 0; nr < 2; ++nr) acc[mr][nr] = (f32x4){0.f, 0.f, 0.f, 0.f};

    float4 apre[8];
    uint4  apre16[4];
    uint4  bpreh[2], bprel[2];

    auto loadA0 = [&](int k0) {
#pragma unroll
        for (int rep = 0; rep < 8; ++rep) {
            const int idx = tid + (rep << 8);
            const int row = idx >> 4;
            const int c4  = (idx & 15) << 2;
            apre[rep] = *(const float4*)(Af32 + (size_t)(row0 + row) * kD + k0 + c4);
        }
    };
    auto loadA1 = [&](int k0) {
#pragma unroll
        for (int rep = 0; rep < 4; ++rep) {
            const int idx = tid + (rep << 8);
            const int row = idx >> 3;
            const int c8  = (idx & 7) << 3;
            apre16[rep] = *(const uint4*)(Af16 + (size_t)(row0 + row) * kD + k0 + c8);
        }
    };
    auto loadB = [&](int k0) {
#pragma unroll
        for (int rep = 0; rep < 2; ++rep) {
            const int idx = tid + (rep << 8);
            const int row = idx >> 3;
            const int c8  = (idx & 7) << 3;
            bpreh[rep] = *(const uint4*)(Bh + (size_t)(col0 + row) * kD + k0 + c8);
            bprel[rep] = *(const uint4*)(Bl + (size_t)(col0 + row) * kD + k0 + c8);
        }
    };

    if (a_kind == 0) loadA0(0); else loadA1(0);
    loadB(0);

    for (int kt = 0; kt < 16; ++kt) {
        __syncthreads();               // prev iter's frag reads done
        // ---- stage prefetched tile into LDS ----
        if (a_kind == 0) {
#pragma unroll
            for (int rep = 0; rep < 8; ++rep) {
                const int idx = tid + (rep << 8);
                const int row = idx >> 4;
                const int c4  = (idx & 15) << 2;
                const float vv[4] = {apre[rep].x, apre[rep].y, apre[rep].z, apre[rep].w};
                _Float16 h4[4], l4[4];
#pragma unroll
                for (int j = 0; j < 4; ++j) split16(vv[j], h4[j], l4[j]);
                *(uint2*)&U.s.Ah[row][c4] = *(uint2*)h4;
                *(uint2*)&U.s.Al[row][c4] = *(uint2*)l4;
            }
        } else {
#pragma unroll
            for (int rep = 0; rep < 4; ++rep) {
                const int idx = tid + (rep << 8);
                const int row = idx >> 3;
                const int c8  = (idx & 7) << 3;
                *(uint4*)&U.s.Ah[row][c8] = apre16[rep];
            }
        }
#pragma unroll
        for (int rep = 0; rep < 2; ++rep) {
            const int idx = tid + (rep << 8);
            const int row = idx >> 3;
            const int c8  = (idx & 7) << 3;
            *(uint4*)&U.s.Bh[row][c8] = bpreh[rep];
            *(uint4*)&U.s.Bl[row][c8] = bprel[rep];
        }
        __syncthreads();

        if (kt < 15) {                 // prefetch next tile (hides HBM/L2 latency)
            const int kn = (kt + 1) << 6;
            if (a_kind == 0) loadA0(kn); else loadA1(kn);
            loadB(kn);
        }

#pragma unroll
        for (int ks = 0; ks < 2; ++ks) {
            f16x8 ah[4], al[4], bhf[2], blf[2];
#pragma unroll
            for (int mr = 0; mr < 4; ++mr)
                ah[mr] = *(const f16x8*)&U.s.Ah[wrow + mr * 16 + m16][ks * 32 + quad * 8];
            if (a_kind == 0) {
#pragma unroll
                for (int mr = 0; mr < 4; ++mr)
                    al[mr] = *(const f16x8*)&U.s.Al[wrow + mr * 16 + m16][ks * 32 + quad * 8];
            }
#pragma unroll
            for (int nr = 0; nr < 2; ++nr) {
                bhf[nr] = *(const f16x8*)&U.s.Bh[wcol + nr * 16 + m16][ks * 32 + quad * 8];
                blf[nr] = *(const f16x8*)&U.s.Bl[wcol + nr * 16 + m16][ks * 32 + quad * 8];
            }
#pragma unroll
            for (int mr = 0; mr < 4; ++mr)
#pragma unroll
                for (int nr = 0; nr < 2; ++nr) {
                    acc[mr][nr] = __builtin_amdgcn_mfma_f32_16x16x32_f16(ah[mr], bhf[nr], acc[mr][nr], 0, 0, 0);
                    acc[mr][nr] = __builtin_amdgcn_mfma_f32_16x16x32_f16(ah[mr], blf[nr], acc[mr][nr], 0, 0, 0);
                    if (a_kind == 0)
                        acc[mr][nr] = __builtin_amdgcn_mfma_f32_16x16x32_f16(al[mr], bhf[nr], acc[mr][nr], 0, 0, 0);
                }
        }
    }

    // ---- epilogue ----
    if (epi == 0) {
#pragma unroll
        for (int mr = 0; mr < 4; ++mr)
#pragma unroll
            for (int nr = 0; nr < 2; ++nr)
#pragma unroll
                for (int r = 0; r < 4; ++r) {
                    const int row = row0 + wrow + mr * 16 + quad * 4 + r;
                    const int col = col0 + wcol + nr * 16 + m16;
                    Cf[(size_t)row * kD + col] = acc[mr][nr][r] + bias[col];
                }
    } else if (epi == 1) {
#pragma unroll
        for (int mr = 0; mr < 4; ++mr)
#pragma unroll
            for (int nr = 0; nr < 2; ++nr)
#pragma unroll
                for (int r = 0; r < 4; ++r) {
                    const int row = row0 + wrow + mr * 16 + quad * 4 + r;
                    const int col = col0 + wcol + nr * 16 + m16;
                    const float v = acc[mr][nr][r] + bias[col];
                    _Float16 h, l; split16(v, h, l);
                    Oh[(size_t)row * kD + col] = h;
                    Ol[(size_t)row * kD + col] = l;
                }
    } else {
        __syncthreads();               // all frag reads done; reuse LDS as T
#pragma unroll
        for (int mr = 0; mr < 4; ++mr)
#pragma unroll
            for (int nr = 0; nr < 2; ++nr)
#pragma unroll
                for (int r = 0; r < 4; ++r) {
                    const int tok = wrow + mr * 16 + quad * 4 + r;   // 0..127
                    const int cl  = wcol + nr * 16 + m16;            // 0..63
                    const float v = acc[mr][nr][r] + bias[col0 + cl];
                    _Float16 h, l; split16(v, h, l);
                    U.t.Th[cl][tok] = h;
                    U.t.Tl[cl][tok] = l;
                }
        __syncthreads();
        const int b  = row0 >> 11;
        const int n0 = row0 & (kN - 1);
#pragma unroll
        for (int rep = 0; rep < 4; ++rep) {
            const int slot = tid + (rep << 8);
            const int d  = slot >> 4;
            const int t8 = (slot & 15) << 3;
            *(uint4*)(Oh + ((size_t)(b * kD + col0 + d)) * kN + n0 + t8) = *(uint4*)&U.t.Th[d][t8];
            *(uint4*)(Ol + ((size_t)(b * kD + col0 + d)) * kN + n0 + t8) = *(uint4*)&U.t.Tl[d][t8];
        }
    }
}

// ---------------------------------------------------------------------------
// MFMA flash attention, fp16 split (hi+lo, 3-term), pre-split inputs.
// Block: 256 threads = 4 waves; wave w owns Q-rows [i0+16w, i0+16w+16).
// 16x16x32 f16 MFMA.  A-frag: m=lane&15, k=quad*8+j.  B-frag: n=lane&15,
// k=quad*8+j.  C/D: col=lane&15, row=quad*4+reg.
// ---------------------------------------------------------------------------
__global__ __launch_bounds__(256)
void attn_f16(const _Float16* __restrict__ Qh, const _Float16* __restrict__ Ql,
              const _Float16* __restrict__ Kh, const _Float16* __restrict__ Kl,
              const _Float16* __restrict__ Vth, const _Float16* __restrict__ Vtl,
              const float* __restrict__ Bg, const float* __restrict__ lam_p,
              _Float16* __restrict__ AOh)
{
    __shared__ _Float16 sKh[64][72], sKl[64][72];
    __shared__ _Float16 sVh[64][72], sVl[64][72];
    __shared__ _Float16 sPh[4][16][72], sPl[4][16][72];

    const int tid  = threadIdx.x;
    const int lane = tid & 63;
    const int w    = tid >> 6;
    const int quad = lane >> 4;
    const int m16  = lane & 15;

    const int qt = blockIdx.x;
    const int bh = blockIdx.y;
    const int b  = bh >> 4;
    const int h  = bh & 15;
    const int i0 = qt << 6;

    const float lam   = *lam_p;
    const float scale = 0.125f;

    // ---- Q A-frags straight from pre-split global (no conversion) ----
    f16x8 qh[2], ql[2];
    {
        const size_t qoff = (size_t)(b * kN + i0 + w * 16 + m16) * kD + h * 64 + quad * 8;
#pragma unroll
        for (int ks = 0; ks < 2; ++ks) {
            qh[ks] = *(const f16x8*)(Qh + qoff + ks * 32);
            ql[ks] = *(const f16x8*)(Ql + qoff + ks * 32);
        }
    }

    f32x4 O[4];
#pragma unroll
    for (int ds = 0; ds < 4; ++ds) O[ds] = (f32x4){0.f, 0.f, 0.f, 0.f};
    float m_run[4], l_run[4];
#pragma unroll
    for (int r = 0; r < 4; ++r) { m_run[r] = -INFINITY; l_run[r] = 0.f; }

    const size_t bgbase = (size_t)b * kN * kN + (size_t)(i0 + w * 16 + quad * 4) * kN;

    for (int jt = 0; jt < kN / 64; ++jt) {
        const int j0 = jt << 6;

        // ---- prefetch tiles (pure copies now) + Bg ----
        uint4 kph[2], kpl[2], vph[2], vpl[2];
#pragma unroll
        for (int rep = 0; rep < 2; ++rep) {
            const int slot = tid + (rep << 8);
            const int row = slot >> 3;
            const int c8  = (slot & 7) << 3;
            const size_t kb = (size_t)(b * kN + j0 + row) * kD + h * 64 + c8;
            const size_t vb = (size_t)(b * kD + h * 64 + row) * kN + j0 + c8;
            kph[rep] = *(const uint4*)(Kh + kb);
            kpl[rep] = *(const uint4*)(Kl + kb);
            vph[rep] = *(const uint4*)(Vth + vb);
            vpl[rep] = *(const uint4*)(Vtl + vb);
        }
        float bg[4][4];
#pragma unroll
        for (int js = 0; js < 4; ++js)
#pragma unroll
            for (int r = 0; r < 4; ++r)
                bg[js][r] = Bg[bgbase + (size_t)r * kN + j0 + js * 16 + m16];

        __syncthreads();
#pragma unroll
        for (int rep = 0; rep < 2; ++rep) {
            const int slot = tid + (rep << 8);
            const int row = slot >> 3;
            const int c8  = (slot & 7) << 3;
            *(uint4*)&sKh[row][c8] = kph[rep];
            *(uint4*)&sKl[row][c8] = kpl[rep];
            *(uint4*)&sVh[row][c8] = vph[rep];
            *(uint4*)&sVl[row][c8] = vpl[rep];
        }
        __syncthreads();

        // ---- S = Q K^T (3-term split-f16) ----
        f32x4 sacc[4];
#pragma unroll
        for (int js = 0; js < 4; ++js) {
            f32x4 s = (f32x4){0.f, 0.f, 0.f, 0.f};
#pragma unroll
            for (int ks = 0; ks < 2; ++ks) {
                const f16x8 khf = *(const f16x8*)&sKh[js * 16 + m16][ks * 32 + quad * 8];
                const f16x8 klf = *(const f16x8*)&sKl[js * 16 + m16][ks * 32 + quad * 8];
                s = __builtin_amdgcn_mfma_f32_16x16x32_f16(qh[ks], khf, s, 0, 0, 0);
                s = __builtin_amdgcn_mfma_f32_16x16x32_f16(qh[ks], klf, s, 0, 0, 0);
                s = __builtin_amdgcn_mfma_f32_16x16x32_f16(ql[ks], khf, s, 0, 0, 0);
            }
            sacc[js] = s;
        }

        // ---- online softmax ----
        float p[4][4];
        float alpha[4];
#pragma unroll
        for (int r = 0; r < 4; ++r) {
            float val[4];
#pragma unroll
            for (int js = 0; js < 4; ++js)
                val[js] = fmaf(lam, bg[js][r], sacc[js][r] * scale);
            float mt = fmaxf(fmaxf(val[0], val[1]), fmaxf(val[2], val[3]));
            mt = fmaxf(mt, __shfl_xor(mt, 1, 16));
            mt = fmaxf(mt, __shfl_xor(mt, 2, 16));
            mt = fmaxf(mt, __shfl_xor(mt, 4, 16));
            mt = fmaxf(mt, __shfl_xor(mt, 8, 16));
            const float mnew = fmaxf(m_run[r], mt);
            alpha[r] = __expf(m_run[r] - mnew);
#pragma unroll
            for (int js = 0; js < 4; ++js) p[js][r] = __expf(val[js] - mnew);
            float ls = (p[0][r] + p[1][r]) + (p[2][r] + p[3][r]);
            ls += __shfl_xor(ls, 1, 16);
            ls += __shfl_xor(ls, 2, 16);
            ls += __shfl_xor(ls, 4, 16);
            ls += __shfl_xor(ls, 8, 16);
            l_run[r] = l_run[r] * alpha[r] + ls;
            m_run[r] = mnew;
        }
#pragma unroll
        for (int ds = 0; ds < 4; ++ds)
#pragma unroll
            for (int r = 0; r < 4; ++r) O[ds][r] *= alpha[r];

        // ---- P -> wave-private LDS (C-layout -> A-layout), split h/l ----
#pragma unroll
        for (int js = 0; js < 4; ++js)
#pragma unroll
            for (int r = 0; r < 4; ++r) {
                _Float16 h, l; split16(p[js][r], h, l);
                sPh[w][quad * 4 + r][js * 16 + m16] = h;
                sPl[w][quad * 4 + r][js * 16 + m16] = l;
            }
        __asm__ volatile("s_waitcnt lgkmcnt(0)" ::: "memory");

        // ---- O += P V (3-term split-f16) ----
#pragma unroll
        for (int ks = 0; ks < 2; ++ks) {
            const f16x8 phf = *(const f16x8*)&sPh[w][m16][ks * 32 + quad * 8];
            const f16x8 plf = *(const f16x8*)&sPl[w][m16][ks * 32 + quad * 8];
#pragma unroll
            for (int ds = 0; ds < 4; ++ds) {
                const f16x8 vhf = *(const f16x8*)&sVh[ds * 16 + m16][ks * 32 + quad * 8];
                const f16x8 vlf = *(const f16x8*)&sVl[ds * 16 + m16][ks * 32 + quad * 8];
                O[ds] = __builtin_amdgcn_mfma_f32_16x16x32_f16(phf, vhf, O[ds], 0, 0, 0);
                O[ds] = __builtin_amdgcn_mfma_f32_16x16x32_f16(phf, vlf, O[ds], 0, 0, 0);
                O[ds] = __builtin_amdgcn_mfma_f32_16x16x32_f16(plf, vhf, O[ds], 0, 0, 0);
            }
        }
    }

    // ---- normalize and store (single fp16 — final GEMM's A operand) ----
    const int orow = b * kN + i0 + w * 16 + quad * 4;
#pragma unroll
    for (int r = 0; r < 4; ++r) {
        const float inv = 1.0f / l_run[r];
#pragma unroll
        for (int ds = 0; ds < 4; ++ds)
            AOh[(size_t)(orow + r) * kD + h * 64 + ds * 16 + m16] =
                (_Float16)(O[ds][r] * inv);
    }
}

// ---------------------------------------------------------------------------
extern "C" void kernel_launch(void* const* d_in, const int* in_sizes, int n_in,
                              void* d_out, int out_size, void* d_ws, size_t ws_size,
                              hipStream_t stream)
{
    (void)in_sizes; (void)n_in; (void)out_size; (void)ws_size;

    const float* x   = (const float*)d_in[0];
    const float* Bg  = (const float*)d_in[1];
    const float* Wq  = (const float*)d_in[2];
    const float* bq  = (const float*)d_in[3];
    const float* Wk  = (const float*)d_in[4];
    const float* bk  = (const float*)d_in[5];
    const float* Wv  = (const float*)d_in[6];
    const float* bv  = (const float*)d_in[7];
    const float* Wo  = (const float*)d_in[8];
    const float* bo  = (const float*)d_in[9];
    const float* lam = (const float*)d_in[10];
    float* out = (float*)d_out;
    _Float16* ws16 = (_Float16*)d_ws;

    // Workspace layout (elems of 2B); total = 67,108,864 B (same as R2 peak).
    constexpr size_t kQKV = (size_t)kM * kD;        // 4,194,304 elems
    constexpr size_t kW   = (size_t)kD * kD;        // 1,048,576 elems
    _Float16* Qh  = ws16;
    _Float16* Ql  = ws16 + kQKV;
    _Float16* Kh  = ws16 + 2 * kQKV;
    _Float16* Kl  = ws16 + 3 * kQKV;
    _Float16* Vth = ws16 + 4 * kQKV;
    _Float16* Vtl = ws16 + 5 * kQKV;
    _Float16* WT  = ws16 + 6 * kQKV;                // Wq/Wk/Wv transposed splits
    _Float16* Wqth = WT,          * Wqtl = WT + kW;
    _Float16* Wkth = WT + 2 * kW, * Wktl = WT + 3 * kW;
    _Float16* Wvth = WT + 4 * kW, * Wvtl = WT + 5 * kW;
    _Float16* AOh  = WT;                            // overlays dead Wq/Wk-t after attn
    _Float16* Woth = WT + 6 * kW, * Wotl = WT + 7 * kW;

    dim3 blk(256);

    // 1) weight prep (one-shot per call)
    dim3 wg(kD / 64, kD / 64);                      // (16,16)
    wsplit_t<<<wg, blk, 0, stream>>>(Wq, Wqth, Wqtl);
    wsplit_t<<<wg, blk, 0, stream>>>(Wk, Wkth, Wktl);
    wsplit_t<<<wg, blk, 0, stream>>>(Wv, Wvth, Wvtl);
    wsplit_t<<<wg, blk, 0, stream>>>(Wo, Woth, Wotl);

    // 2) projections (split-fp16 MFMA)
    dim3 gg(kD / 64, kM / 128);                     // (16, 32) = 512 blocks
    gemm_split<<<gg, blk, 0, stream>>>(x, nullptr, Wqth, Wqtl, bq,
                                       nullptr, Qh, Ql, 0, 1);
    gemm_split<<<gg, blk, 0, stream>>>(x, nullptr, Wkth, Wktl, bk,
                                       nullptr, Kh, Kl, 0, 1);
    gemm_split<<<gg, blk, 0, stream>>>(x, nullptr, Wvth, Wvtl, bv,
                                       nullptr, Vth, Vtl, 0, 2);

    // 3) attention
    dim3 ag(kN / 64, kB * kH);                      // (32, 32)
    attn_f16<<<ag, blk, 0, stream>>>(Qh, Ql, Kh, Kl, Vth, Vtl, Bg, lam, AOh);

    // 4) output projection (A = AOh single fp16, 2-term)
    gemm_split<<<gg, blk, 0, stream>>>(nullptr, AOh, Woth, Wotl, bo,
                                       out, nullptr, nullptr, 1, 0);
}